// Round 3
// baseline (480.767 us; speedup 1.0000x reference)
//
#include <hip/hip_runtime.h>

typedef __attribute__((ext_vector_type(8))) short bf16x8;
typedef __attribute__((ext_vector_type(4))) float f32x4;

#define MFMA_BF16(a, b, c) __builtin_amdgcn_mfma_f32_16x16x32_bf16((a), (b), (c), 0, 0, 0)

__device__ __forceinline__ unsigned short bf16rn(float f) {
  unsigned u = __builtin_bit_cast(unsigned, f);
  u += 0x7fffu + ((u >> 16) & 1u);
  return (unsigned short)(u >> 16);
}

__device__ __forceinline__ void gld_lds16(const void* g, void* l) {
  __builtin_amdgcn_global_load_lds((const __attribute__((address_space(1))) void*)g,
                                   (__attribute__((address_space(3))) void*)l, 16, 0, 0);
}

// ---------------- weight convert + transpose: W[K][N] f32 -> W^T[N][K] bf16 ----------------
__global__ __launch_bounds__(256) void convT_kernel(
    const float* __restrict__ wq, const float* __restrict__ wk,
    const float* __restrict__ wv, const float* __restrict__ wo,
    const float* __restrict__ wfc, const float* __restrict__ wpj,
    unsigned short* __restrict__ wsb)
{
  const int bid = blockIdx.x;
  const float* src; unsigned short* dst; int K, N, lb;
  if (bid < 1024) {
    const int m = bid >> 8; lb = bid & 255; K = 1024; N = 1024;
    src = (m == 0) ? wq : (m == 1) ? wk : (m == 2) ? wv : wo;
    dst = wsb + (size_t)m * 1048576u;
  } else if (bid < 2048) {
    lb = bid - 1024; K = 1024; N = 4096; src = wfc; dst = wsb + 4194304u;
  } else {
    lb = bid - 2048; K = 4096; N = 1024; src = wpj; dst = wsb + 8388608u;
  }
  const int tiles_k = K >> 6;
  const int tk = lb % tiles_k, tn = lb / tiles_k;
  const int k0 = tk << 6, n0 = tn << 6;
  const int t = threadIdx.x, kq = t & 15, nq = t >> 4;
  float4 r[4];
#pragma unroll
  for (int i = 0; i < 4; ++i)
    r[i] = *(const float4*)(src + (size_t)(k0 + kq * 4 + i) * N + n0 + nq * 4);
#pragma unroll
  for (int j = 0; j < 4; ++j) {
    ushort4 o;
    o.x = bf16rn(((const float*)&r[0])[j]);
    o.y = bf16rn(((const float*)&r[1])[j]);
    o.z = bf16rn(((const float*)&r[2])[j]);
    o.w = bf16rn(((const float*)&r[3])[j]);
    *(ushort4*)(dst + (size_t)(n0 + nq * 4 + j) * K + k0 + kq * 4) = o;
  }
}

// ---------------- layernorm: f32 [rows][1024] -> bf16 ----------------
__global__ __launch_bounds__(256) void ln_kernel(
    const float* __restrict__ x, const float* __restrict__ sc,
    const float* __restrict__ sh, unsigned short* __restrict__ out)
{
  const int row = blockIdx.x, t = threadIdx.x;
  const float4 v = *(const float4*)(x + (size_t)row * 1024 + t * 4);
  float s = v.x + v.y + v.z + v.w;
  float q = v.x * v.x + v.y * v.y + v.z * v.z + v.w * v.w;
#pragma unroll
  for (int off = 1; off < 64; off <<= 1) { s += __shfl_xor(s, off); q += __shfl_xor(q, off); }
  __shared__ float ps[4], pq[4];
  if ((t & 63) == 0) { ps[t >> 6] = s; pq[t >> 6] = q; }
  __syncthreads();
  s = ps[0] + ps[1] + ps[2] + ps[3];
  q = pq[0] + pq[1] + pq[2] + pq[3];
  const float mean = s * (1.f / 1024.f);
  const float var = q * (1.f / 1024.f) - mean * mean;
  const float inv = rsqrtf(var + 1e-5f);
  const float4 scv = *(const float4*)(sc + t * 4);
  const float4 shv = *(const float4*)(sh + t * 4);
  ushort4 o;
  o.x = bf16rn((v.x - mean) * inv * scv.x + shv.x);
  o.y = bf16rn((v.y - mean) * inv * scv.y + shv.y);
  o.z = bf16rn((v.z - mean) * inv * scv.z + shv.z);
  o.w = bf16rn((v.w - mean) * inv * scv.w + shv.w);
  *(ushort4*)(out + (size_t)row * 1024 + t * 4) = o;
}

// ---------------- old 128x128 GEMM, kept only for EPI=1 (V with transposed store) ---------
template<int EPI>
__global__ __launch_bounds__(256) void gemm_bt(
    const unsigned short* __restrict__ A, const unsigned short* __restrict__ Bt,
    int M, int N, int K,
    unsigned short* __restrict__ outb, float* __restrict__ outf,
    const float* __restrict__ bias, const float* __restrict__ resid)
{
  __shared__ char smem[(EPI == 1) ? 36864 : 16384];
  const int t = threadIdx.x;
  const int lane = t & 63, w = t >> 6;
  const int g = lane >> 4, l15 = lane & 15;
  const int wr = w >> 1, wc = w & 1;
  const int m0 = blockIdx.x * 128, n0 = blockIdx.y * 128;

  f32x4 acc[4][4] = {};

  const int nkt = K >> 5;
  for (int kt = 0; kt < nkt; ++kt) {
    const int k0 = kt << 5;
    __syncthreads();
#pragma unroll
    for (int it = 0; it < 2; ++it) {
      const int c = it * 256 + t;
      const int row = c >> 2;
      const int ce = (c & 3) << 3;
      gld_lds16(A + (size_t)(m0 + row) * K + k0 + ce,
                smem + ((it * 256 + w * 64) << 4));
      gld_lds16(Bt + (size_t)(n0 + row) * K + k0 + ce,
                smem + 8192 + ((it * 256 + w * 64) << 4));
    }
    __syncthreads();
    bf16x8 a[4], b[4];
#pragma unroll
    for (int mi = 0; mi < 4; ++mi)
      a[mi] = *(const bf16x8*)(smem + (wr * 64 + mi * 16 + l15) * 64 + g * 16);
#pragma unroll
    for (int ni = 0; ni < 4; ++ni)
      b[ni] = *(const bf16x8*)(smem + 8192 + (wc * 64 + ni * 16 + l15) * 64 + g * 16);
#pragma unroll
    for (int mi = 0; mi < 4; ++mi)
#pragma unroll
      for (int ni = 0; ni < 4; ++ni)
        acc[mi][ni] = MFMA_BF16(a[mi], b[ni], acc[mi][ni]);
  }

  if constexpr (EPI == 1) {  // transposed store for V
    __syncthreads();
    unsigned short* T = (unsigned short*)(smem + w * 9216);  // [64 n][72 m-padded]
#pragma unroll
    for (int mi = 0; mi < 4; ++mi)
#pragma unroll
      for (int ni = 0; ni < 4; ++ni)
#pragma unroll
        for (int r = 0; r < 4; ++r)
          T[(ni * 16 + l15) * 72 + mi * 16 + 4 * g + r] = bf16rn(acc[mi][ni][r]);
    asm volatile("s_waitcnt lgkmcnt(0)" ::: "memory");
    const int bidx = m0 >> 11;
    const int srow = (m0 & 2047) + wr * 64 + ((lane & 7) << 3);
#pragma unroll
    for (int rr = 0; rr < 8; ++rr) {
      const int trow = rr * 8 + (lane >> 3);
      bf16x8 v = *(const bf16x8*)((char*)T + trow * 144 + ((lane & 7) << 4));
      *(bf16x8*)(outb + (size_t)(bidx * 1024 + n0 + wc * 64 + trow) * 2048 + srow) = v;
    }
  }
}

// ---------------- 256x256 BK=64 phase-split GEMM (T1/T2/T3-lite/T5) ----------------------
// EPI 0: bf16 store; 2: f32 = acc + bias + resid; 3: bf16 = gelu(acc + bias)
template<int EPI>
__global__ __launch_bounds__(512, 2) void gemm256(
    const unsigned short* __restrict__ A, const unsigned short* __restrict__ Bt,
    int M, int N, int K, int nTm,
    unsigned short* __restrict__ outb, float* __restrict__ outf,
    const float* __restrict__ bias, const float* __restrict__ resid)
{
  extern __shared__ char smem[];  // 131072: [buf0: A 32K | B 32K][buf1: A 32K | B 32K]
  const int t = threadIdx.x;
  const int lane = t & 63, w = t >> 6;
  const int g = lane >> 4, l15 = lane & 15;
  const int wr = w >> 2, wc = w & 3;  // 2 x 4 wave grid; wave tile 128 x 64
  const int nwg = gridDim.x;
  const int bid = blockIdx.x;
  const int idx = (bid & 7) * (nwg >> 3) + (bid >> 3);  // XCD swizzle (nwg % 8 == 0)
  const int tm = idx % nTm, tn = idx / nTm;
  const int m0 = tm << 8, n0 = tn << 8;

  // staging: thread covers row (t>>3), 16B slot (t&7), source col pre-swizzled
  const int rw = (t >> 3) & 7;
  const int colsw = ((t & 7) ^ rw) << 3;  // element offset
  const unsigned short* Asrc = A + (size_t)(m0 + (t >> 3)) * K + colsw;
  const unsigned short* Bsrc = Bt + (size_t)(n0 + (t >> 3)) * K + colsw;
  const int ldsw = w << 10;
  const int xr = (l15 & 7) << 4;  // frag-read XOR swizzle

  f32x4 acc[8][4] = {};
  const int NT = K >> 6;

  // prologue: stage K-tile 0 into buf0
#pragma unroll
  for (int j = 0; j < 4; ++j)
    gld_lds16(Asrc + (size_t)(j * 64) * K, smem + j * 8192 + ldsw);
#pragma unroll
  for (int j = 0; j < 4; ++j)
    gld_lds16(Bsrc + (size_t)(j * 64) * K, smem + 32768 + j * 8192 + ldsw);
  asm volatile("s_waitcnt vmcnt(0)" ::: "memory");
  __builtin_amdgcn_s_barrier();

  for (int kt = 0; kt < NT; ++kt) {
    const int cb = (kt & 1) << 16;
    const int ob = cb ^ 65536;
    const bool pf = (kt + 1 < NT);
    const int kcol = (kt + 1) << 6;
#pragma unroll
    for (int q = 0; q < 4; ++q) {
      const int qm = q & 1, qn = q >> 1;
      bf16x8 af[4][2], bfr[2][2];
#pragma unroll
      for (int mi = 0; mi < 4; ++mi) {
        const int row = wr * 128 + qm * 64 + mi * 16 + l15;
#pragma unroll
        for (int ks = 0; ks < 2; ++ks)
          af[mi][ks] = *(const bf16x8*)(smem + cb + ((row * 128 + ks * 64 + g * 16) ^ xr));
      }
#pragma unroll
      for (int ni = 0; ni < 2; ++ni) {
        const int row = wc * 64 + qn * 32 + ni * 16 + l15;
#pragma unroll
        for (int ks = 0; ks < 2; ++ks)
          bfr[ni][ks] = *(const bf16x8*)(smem + cb + 32768 +
                                         ((row * 128 + ks * 64 + g * 16) ^ xr));
      }
      if (q == 0 && pf) {
#pragma unroll
        for (int j = 0; j < 4; ++j)
          gld_lds16(Asrc + (size_t)(j * 64) * K + kcol, smem + ob + j * 8192 + ldsw);
      }
      if (q == 1 && pf) {
#pragma unroll
        for (int j = 0; j < 4; ++j)
          gld_lds16(Bsrc + (size_t)(j * 64) * K + kcol, smem + ob + 32768 + j * 8192 + ldsw);
      }
      __builtin_amdgcn_s_barrier();
      __builtin_amdgcn_s_setprio(1);
#pragma unroll
      for (int mi = 0; mi < 4; ++mi)
#pragma unroll
        for (int ni = 0; ni < 2; ++ni) {
          acc[qm * 4 + mi][qn * 2 + ni] =
              MFMA_BF16(af[mi][0], bfr[ni][0], acc[qm * 4 + mi][qn * 2 + ni]);
          acc[qm * 4 + mi][qn * 2 + ni] =
              MFMA_BF16(af[mi][1], bfr[ni][1], acc[qm * 4 + mi][qn * 2 + ni]);
        }
      __builtin_amdgcn_s_setprio(0);
      if (q < 3) __builtin_amdgcn_s_barrier();
    }
    asm volatile("s_waitcnt vmcnt(0)" ::: "memory");
    __builtin_amdgcn_s_barrier();
  }

  // epilogue; acc[i][j]: rows (i>>2)*64+(i&3)*16, cols (j>>1)*32+(j&1)*16 of the wave tile
  if constexpr (EPI == 2) {
#pragma unroll
    for (int mi = 0; mi < 8; ++mi) {
      const int ro = ((mi >> 2) << 6) + ((mi & 3) << 4);
#pragma unroll
      for (int ni = 0; ni < 4; ++ni) {
        const int co = ((ni >> 1) << 5) + ((ni & 1) << 4);
        const int n = n0 + wc * 64 + co + l15;
        const float bn = bias[n];
#pragma unroll
        for (int r = 0; r < 4; ++r) {
          const size_t m = m0 + wr * 128 + ro + g * 4 + r;
          outf[m * N + n] = acc[mi][ni][r] + bn + resid[m * N + n];
        }
      }
    }
  } else {
    char* wsl = smem + w * 16384;  // per-wave bounce [128 rows][64 cols] bf16
#pragma unroll
    for (int mi = 0; mi < 8; ++mi) {
      const int ro = ((mi >> 2) << 6) + ((mi & 3) << 4);
#pragma unroll
      for (int ni = 0; ni < 4; ++ni) {
        const int co = ((ni >> 1) << 5) + ((ni & 1) << 4);
        float bn = 0.f;
        if constexpr (EPI == 3) bn = bias[n0 + wc * 64 + co + l15];
#pragma unroll
        for (int r = 0; r < 4; ++r) {
          float v = acc[mi][ni][r];
          if constexpr (EPI == 3) {
            v += bn;
            const float inner = 0.7978845608028654f * (v + 0.044715f * v * v * v);
            v = 0.5f * v * (1.0f + tanhf(inner));
          }
          *(unsigned short*)(wsl + (ro + g * 4 + r) * 128 + (co + l15) * 2) = bf16rn(v);
        }
      }
    }
    // same-wave LDS RAW ordered by in-order DS pipe + compiler lgkmcnt
#pragma unroll
    for (int s = 0; s < 16; ++s) {
      const int row = s * 8 + (lane >> 3);
      bf16x8 vv = *(const bf16x8*)(wsl + row * 128 + (lane & 7) * 16);
      *(bf16x8*)(outb + (size_t)(m0 + wr * 128 + row) * N + n0 + wc * 64 + (lane & 7) * 8) = vv;
    }
  }
}

// ---------------- flash attention, causal, D=64, QB=128 (4 waves x 32 rows), KB=64 --------
// Q/K come from the fused QK buffer [8192][2048]: Q at cols 0-1023, K at cols 1024-2047.
__global__ __launch_bounds__(256) void attn_kernel(
    const unsigned short* __restrict__ qg, const unsigned short* __restrict__ kg,
    const unsigned short* __restrict__ vT, unsigned short* __restrict__ ctx)
{
  __shared__ char smem[34816];  // K 8KB | V_T 8KB | P 4x4608
  const int bh = blockIdx.x, b = bh >> 4, h = bh & 15;
  const int t = threadIdx.x, lane = t & 63, w = t >> 6, g = lane >> 4, l15 = lane & 15;
  char* Ks = smem;
  char* Vs = smem + 8192;
  char* Ps = smem + 16384 + w * 4608;

  const float SC = 0.18033688011112042f;  // 0.125 * log2(e)

  for (int pass = 0; pass < 2; ++pass) {
    const int qt = pass ? 15 - (int)blockIdx.y : (int)blockIdx.y;
    const int q0 = qt << 7;
    const int q0w = q0 + w * 32;

    bf16x8 qf[2][2];
#pragma unroll
    for (int mi = 0; mi < 2; ++mi)
#pragma unroll
      for (int ks = 0; ks < 2; ++ks)
        qf[mi][ks] = *(const bf16x8*)(qg + (size_t)(b * 2048 + q0w + mi * 16 + l15) * 2048 +
                                      h * 64 + ks * 32 + g * 8);

    f32x4 acc[2][4] = {};
    float lsum[2][4] = {};

    const int ntile = 2 * qt + 2;
    for (int kt = 0; kt < ntile; ++kt) {
      const int kv0 = kt << 6;
      __syncthreads();
#pragma unroll
      for (int it = 0; it < 2; ++it) {
        const int c = it * 256 + t;
        const int row = c >> 3;
        const int wb = (c & 7) << 4;
        const int sw = (wb ^ ((row & 7) << 4)) >> 1;
        gld_lds16(kg + (size_t)(b * 2048 + kv0 + row) * 2048 + h * 64 + sw,
                  Ks + ((it * 256 + w * 64) << 4));
        gld_lds16(vT + (size_t)(b * 1024 + h * 64 + row) * 2048 + kv0 + sw,
                  Vs + ((it * 256 + w * 64) << 4));
      }
      __syncthreads();

      f32x4 sf[2][4] = {};
#pragma unroll
      for (int nb = 0; nb < 4; ++nb) {
        const int krow = nb * 16 + l15;
#pragma unroll
        for (int ks = 0; ks < 2; ++ks) {
          bf16x8 kf = *(const bf16x8*)(Ks + krow * 128 +
                                       (((ks * 32 + g * 8) << 1) ^ ((krow & 7) << 4)));
          sf[0][nb] = MFMA_BF16(qf[0][ks], kf, sf[0][nb]);
          sf[1][nb] = MFMA_BF16(qf[1][ks], kf, sf[1][nb]);
        }
      }
      if (kv0 + 63 > q0w) {
#pragma unroll
        for (int mi = 0; mi < 2; ++mi)
#pragma unroll
          for (int nb = 0; nb < 4; ++nb)
#pragma unroll
            for (int r = 0; r < 4; ++r) {
              const int qq = q0w + mi * 16 + 4 * g + r;
              const int kk = kv0 + nb * 16 + l15;
              if (kk > qq) sf[mi][nb][r] = -__builtin_inff();
            }
      }
#pragma unroll
      for (int mi = 0; mi < 2; ++mi)
#pragma unroll
        for (int nb = 0; nb < 4; ++nb)
#pragma unroll
          for (int r = 0; r < 4; ++r) {
            const float p = exp2f(__builtin_fmaf(sf[mi][nb][r], SC, -4.0f));
            sf[mi][nb][r] = p;
            lsum[mi][r] += p;
          }
#pragma unroll
      for (int mi = 0; mi < 2; ++mi)
#pragma unroll
        for (int nb = 0; nb < 4; ++nb)
#pragma unroll
          for (int r = 0; r < 4; ++r)
            *(unsigned short*)(Ps + (mi * 16 + 4 * g + r) * 144 + ((nb * 16 + l15) << 1)) =
                bf16rn(sf[mi][nb][r]);
      asm volatile("s_waitcnt lgkmcnt(0)" ::: "memory");
#pragma unroll
      for (int mi = 0; mi < 2; ++mi)
#pragma unroll
        for (int ks = 0; ks < 2; ++ks) {
          bf16x8 pa = *(const bf16x8*)(Ps + (mi * 16 + l15) * 144 + ((ks * 32 + g * 8) << 1));
#pragma unroll
          for (int nb = 0; nb < 4; ++nb) {
            const int drow = nb * 16 + l15;
            bf16x8 vb = *(const bf16x8*)(Vs + drow * 128 +
                                         (((ks * 32 + g * 8) << 1) ^ ((drow & 7) << 4)));
            acc[mi][nb] = MFMA_BF16(pa, vb, acc[mi][nb]);
          }
        }
    }
#pragma unroll
    for (int mi = 0; mi < 2; ++mi)
#pragma unroll
      for (int r = 0; r < 4; ++r) {
        float s = lsum[mi][r];
        s += __shfl_xor(s, 1);
        s += __shfl_xor(s, 2);
        s += __shfl_xor(s, 4);
        s += __shfl_xor(s, 8);
        lsum[mi][r] = s;
      }
#pragma unroll
    for (int mi = 0; mi < 2; ++mi) {
      float inv[4];
#pragma unroll
      for (int r = 0; r < 4; ++r) inv[r] = 1.0f / lsum[mi][r];
#pragma unroll
      for (int nb = 0; nb < 4; ++nb)
#pragma unroll
        for (int r = 0; r < 4; ++r)
          ctx[(size_t)(b * 2048 + q0w + mi * 16 + 4 * g + r) * 1024 + h * 64 + nb * 16 + l15] =
              bf16rn(acc[mi][nb][r] * inv[r]);
    }
  }
}

extern "C" void kernel_launch(void* const* d_in, const int* in_sizes, int n_in,
                              void* d_out, int out_size, void* d_ws, size_t ws_size,
                              hipStream_t stream)
{
  const float* x   = (const float*)d_in[0];
  const float* l1s = (const float*)d_in[1];
  const float* l1b = (const float*)d_in[2];
  const float* l2s = (const float*)d_in[3];
  const float* l2b = (const float*)d_in[4];
  const float* Wq  = (const float*)d_in[5];
  const float* Wk  = (const float*)d_in[6];
  const float* Wv  = (const float*)d_in[7];
  const float* Wo  = (const float*)d_in[8];
  const float* bo  = (const float*)d_in[9];
  const float* Wfc = (const float*)d_in[10];
  const float* bfc = (const float*)d_in[11];
  const float* Wpj = (const float*)d_in[12];
  const float* bpj = (const float*)d_in[13];
  float* out = (float*)d_out;
  char* ws = (char*)d_ws;

  // workspace layout (bytes)
  unsigned short* wT   = (unsigned short*)ws;                // 24MB: [wqT wkT][wvT][woT][wfcT][wpjT]
  unsigned short* wqkT = wT;                                 // [2048][1024] fused Q|K
  unsigned short* wvT  = wT + 2097152u;
  unsigned short* woT  = wT + 3145728u;
  unsigned short* wfcT = wT + 4194304u;
  unsigned short* wpjT = wT + 8388608u;
  unsigned short* ln1x = (unsigned short*)(ws + 25165824u);  // 16MB
  unsigned short* qkb  = (unsigned short*)(ws + 41943040u);  // 32MB [8192][2048] fused Q|K out
  unsigned short* vTb  = (unsigned short*)(ws + 75497472u);  // 16MB [b*1024+h*64+d][2048]
  unsigned short* ctx  = (unsigned short*)(ws + 92274688u);  // 16MB (reused as ln2x)
  unsigned short* ln2x = ctx;
  float* hbuf          = (float*)(ws + 109051904u);          // 32MB
  unsigned short* fcb  = (unsigned short*)(ws + 25165824u);  // 64MB, reuses ln1x..vTb region

  convT_kernel<<<3072, 256, 0, stream>>>(Wq, Wk, Wv, Wo, Wfc, Wpj, wT);
  ln_kernel<<<8192, 256, 0, stream>>>(x, l1s, l1b, ln1x);
  // fused Q+K GEMM: [8192][1024] x [2048][1024]^T -> [8192][2048]
  gemm256<0><<<256, 512, 131072, stream>>>(ln1x, wqkT, 8192, 2048, 1024, 32,
                                           qkb, nullptr, nullptr, nullptr);
  gemm_bt<1><<<dim3(64, 8), 256, 0, stream>>>(ln1x, wvT, 8192, 1024, 1024,
                                              vTb, nullptr, nullptr, nullptr);
  attn_kernel<<<dim3(64, 8), 256, 0, stream>>>(qkb, qkb + 1024, vTb, ctx);
  gemm256<2><<<128, 512, 131072, stream>>>(ctx, woT, 8192, 1024, 1024, 32,
                                           nullptr, hbuf, bo, x);
  ln_kernel<<<8192, 256, 0, stream>>>(hbuf, l2s, l2b, ln2x);
  gemm256<3><<<512, 512, 131072, stream>>>(ln2x, wfcT, 8192, 4096, 1024, 32,
                                           fcb, nullptr, bfc, nullptr);
  gemm256<2><<<128, 512, 131072, stream>>>(fcb, wpjT, 8192, 1024, 4096, 32,
                                           nullptr, out, bpj, hbuf);
}

// Round 4
// 413.731 us; speedup vs baseline: 1.1620x; 1.1620x over previous
//
#include <hip/hip_runtime.h>

typedef __attribute__((ext_vector_type(8))) short bf16x8;
typedef __attribute__((ext_vector_type(4))) float f32x4;

#define MFMA_BF16(a, b, c) __builtin_amdgcn_mfma_f32_16x16x32_bf16((a), (b), (c), 0, 0, 0)

__device__ __forceinline__ unsigned short bf16rn(float f) {
  unsigned u = __builtin_bit_cast(unsigned, f);
  u += 0x7fffu + ((u >> 16) & 1u);
  return (unsigned short)(u >> 16);
}

__device__ __forceinline__ void gld_lds16(const void* g, void* l) {
  __builtin_amdgcn_global_load_lds((const __attribute__((address_space(1))) void*)g,
                                   (__attribute__((address_space(3))) void*)l, 16, 0, 0);
}

// ---------------- weight convert + transpose: W[K][N] f32 -> W^T[N][K] bf16 ----------------
__global__ __launch_bounds__(256) void convT_kernel(
    const float* __restrict__ wq, const float* __restrict__ wk,
    const float* __restrict__ wv, const float* __restrict__ wo,
    const float* __restrict__ wfc, const float* __restrict__ wpj,
    unsigned short* __restrict__ wsb)
{
  const int bid = blockIdx.x;
  const float* src; unsigned short* dst; int K, N, lb;
  if (bid < 1024) {
    const int m = bid >> 8; lb = bid & 255; K = 1024; N = 1024;
    src = (m == 0) ? wq : (m == 1) ? wk : (m == 2) ? wv : wo;
    dst = wsb + (size_t)m * 1048576u;
  } else if (bid < 2048) {
    lb = bid - 1024; K = 1024; N = 4096; src = wfc; dst = wsb + 4194304u;
  } else {
    lb = bid - 2048; K = 4096; N = 1024; src = wpj; dst = wsb + 8388608u;
  }
  const int tiles_k = K >> 6;
  const int tk = lb % tiles_k, tn = lb / tiles_k;
  const int k0 = tk << 6, n0 = tn << 6;
  const int t = threadIdx.x, kq = t & 15, nq = t >> 4;
  float4 r[4];
#pragma unroll
  for (int i = 0; i < 4; ++i)
    r[i] = *(const float4*)(src + (size_t)(k0 + kq * 4 + i) * N + n0 + nq * 4);
#pragma unroll
  for (int j = 0; j < 4; ++j) {
    ushort4 o;
    o.x = bf16rn(((const float*)&r[0])[j]);
    o.y = bf16rn(((const float*)&r[1])[j]);
    o.z = bf16rn(((const float*)&r[2])[j]);
    o.w = bf16rn(((const float*)&r[3])[j]);
    *(ushort4*)(dst + (size_t)(n0 + nq * 4 + j) * K + k0 + kq * 4) = o;
  }
}

// ---------------- layernorm: f32 [rows][1024] -> bf16 ----------------
__global__ __launch_bounds__(256) void ln_kernel(
    const float* __restrict__ x, const float* __restrict__ sc,
    const float* __restrict__ sh, unsigned short* __restrict__ out)
{
  const int row = blockIdx.x, t = threadIdx.x;
  const float4 v = *(const float4*)(x + (size_t)row * 1024 + t * 4);
  float s = v.x + v.y + v.z + v.w;
  float q = v.x * v.x + v.y * v.y + v.z * v.z + v.w * v.w;
#pragma unroll
  for (int off = 1; off < 64; off <<= 1) { s += __shfl_xor(s, off); q += __shfl_xor(q, off); }
  __shared__ float ps[4], pq[4];
  if ((t & 63) == 0) { ps[t >> 6] = s; pq[t >> 6] = q; }
  __syncthreads();
  s = ps[0] + ps[1] + ps[2] + ps[3];
  q = pq[0] + pq[1] + pq[2] + pq[3];
  const float mean = s * (1.f / 1024.f);
  const float var = q * (1.f / 1024.f) - mean * mean;
  const float inv = rsqrtf(var + 1e-5f);
  const float4 scv = *(const float4*)(sc + t * 4);
  const float4 shv = *(const float4*)(sh + t * 4);
  ushort4 o;
  o.x = bf16rn((v.x - mean) * inv * scv.x + shv.x);
  o.y = bf16rn((v.y - mean) * inv * scv.y + shv.y);
  o.z = bf16rn((v.z - mean) * inv * scv.z + shv.z);
  o.w = bf16rn((v.w - mean) * inv * scv.w + shv.w);
  *(ushort4*)(out + (size_t)row * 1024 + t * 4) = o;
}

// ---------------- old 128x128 GEMM, kept only for EPI=1 (V with transposed store) ---------
template<int EPI>
__global__ __launch_bounds__(256) void gemm_bt(
    const unsigned short* __restrict__ A, const unsigned short* __restrict__ Bt,
    int M, int N, int K,
    unsigned short* __restrict__ outb, float* __restrict__ outf,
    const float* __restrict__ bias, const float* __restrict__ resid)
{
  __shared__ char smem[(EPI == 1) ? 36864 : 16384];
  const int t = threadIdx.x;
  const int lane = t & 63, w = t >> 6;
  const int g = lane >> 4, l15 = lane & 15;
  const int wr = w >> 1, wc = w & 1;
  const int m0 = blockIdx.x * 128, n0 = blockIdx.y * 128;

  f32x4 acc[4][4] = {};

  const int nkt = K >> 5;
  for (int kt = 0; kt < nkt; ++kt) {
    const int k0 = kt << 5;
    __syncthreads();
#pragma unroll
    for (int it = 0; it < 2; ++it) {
      const int c = it * 256 + t;
      const int row = c >> 2;
      const int ce = (c & 3) << 3;
      gld_lds16(A + (size_t)(m0 + row) * K + k0 + ce,
                smem + ((it * 256 + w * 64) << 4));
      gld_lds16(Bt + (size_t)(n0 + row) * K + k0 + ce,
                smem + 8192 + ((it * 256 + w * 64) << 4));
    }
    __syncthreads();
    bf16x8 a[4], b[4];
#pragma unroll
    for (int mi = 0; mi < 4; ++mi)
      a[mi] = *(const bf16x8*)(smem + (wr * 64 + mi * 16 + l15) * 64 + g * 16);
#pragma unroll
    for (int ni = 0; ni < 4; ++ni)
      b[ni] = *(const bf16x8*)(smem + 8192 + (wc * 64 + ni * 16 + l15) * 64 + g * 16);
#pragma unroll
    for (int mi = 0; mi < 4; ++mi)
#pragma unroll
      for (int ni = 0; ni < 4; ++ni)
        acc[mi][ni] = MFMA_BF16(a[mi], b[ni], acc[mi][ni]);
  }

  if constexpr (EPI == 1) {  // transposed store for V
    __syncthreads();
    unsigned short* T = (unsigned short*)(smem + w * 9216);  // [64 n][72 m-padded]
#pragma unroll
    for (int mi = 0; mi < 4; ++mi)
#pragma unroll
      for (int ni = 0; ni < 4; ++ni)
#pragma unroll
        for (int r = 0; r < 4; ++r)
          T[(ni * 16 + l15) * 72 + mi * 16 + 4 * g + r] = bf16rn(acc[mi][ni][r]);
    asm volatile("s_waitcnt lgkmcnt(0)" ::: "memory");
    const int bidx = m0 >> 11;
    const int srow = (m0 & 2047) + wr * 64 + ((lane & 7) << 3);
#pragma unroll
    for (int rr = 0; rr < 8; ++rr) {
      const int trow = rr * 8 + (lane >> 3);
      bf16x8 v = *(const bf16x8*)((char*)T + trow * 144 + ((lane & 7) << 4));
      *(bf16x8*)(outb + (size_t)(bidx * 1024 + n0 + wc * 64 + trow) * 2048 + srow) = v;
    }
  }
}

// ---------------- BMx256 BK=64 phase-split GEMM (L2-local stripes + T2/T5) ---------------
// EPI 0: bf16 store; 2: f32 = acc + bias + resid; 3: bf16 = gelu(acc + bias)
// Tile map: XCD x (= bid&7) owns tm-stripe [(x)*S, x*S+S) x all tn, S = 2^stripeLg.
template<int EPI, int BM>
__global__ __launch_bounds__(512, 2) void gemm256(
    const unsigned short* __restrict__ A, const unsigned short* __restrict__ Bt,
    int M, int N, int K, int stripeLg,
    unsigned short* __restrict__ outb, float* __restrict__ outf,
    const float* __restrict__ bias, const float* __restrict__ resid)
{
  extern __shared__ char smem[];
  constexpr int WTR = BM / 2;        // wave tile rows
  constexpr int MH = WTR / 32;       // m-frags per quadrant (4 or 2)
  constexpr int MF = 2 * MH;         // m-frags per wave
  constexpr int ASZ = BM * 128;      // A bytes per K-tile buffer
  constexpr int SBUF = ASZ + 32768;  // K-tile buffer stride (A + B)
  constexpr int AJ = BM / 64;        // A staging chunks

  const int t = threadIdx.x;
  const int lane = t & 63, w = t >> 6;
  const int g = lane >> 4, l15 = lane & 15;
  const int wr = w >> 2, wc = w & 3;  // 2 x 4 wave grid; wave tile WTR x 64
  const int bid = blockIdx.x;
  const int tm = ((bid & 7) << stripeLg) + ((bid >> 3) & ((1 << stripeLg) - 1));
  const int tn = bid >> (3 + stripeLg);
  const int m0 = tm * BM, n0 = tn << 8;

  // staging: thread covers row (t>>3), 16B slot (t&7), source col pre-swizzled
  const int rw = (t >> 3) & 7;
  const int colsw = ((t & 7) ^ rw) << 3;  // element offset
  const unsigned short* Asrc = A + (size_t)(m0 + (t >> 3)) * K + colsw;
  const unsigned short* Bsrc = Bt + (size_t)(n0 + (t >> 3)) * K + colsw;
  const int ldsw = w << 10;
  const int xr = (l15 & 7) << 4;  // frag-read XOR swizzle

  f32x4 acc[MF][4] = {};
  const int NT = K >> 6;

  // prologue: stage K-tile 0 into buf0
#pragma unroll
  for (int j = 0; j < AJ; ++j)
    gld_lds16(Asrc + (size_t)(j * 64) * K, smem + j * 8192 + ldsw);
#pragma unroll
  for (int j = 0; j < 4; ++j)
    gld_lds16(Bsrc + (size_t)(j * 64) * K, smem + ASZ + j * 8192 + ldsw);
  asm volatile("s_waitcnt vmcnt(0)" ::: "memory");
  __builtin_amdgcn_s_barrier();

  for (int kt = 0; kt < NT; ++kt) {
    const int cb = (kt & 1) * SBUF;
    const int ob = SBUF - cb;
    const bool pf = (kt + 1 < NT);
    const int kcol = (kt + 1) << 6;
#pragma unroll
    for (int q = 0; q < 4; ++q) {
      const int qm = q & 1, qn = q >> 1;
      bf16x8 af[MH][2], bfr[2][2];
#pragma unroll
      for (int mi = 0; mi < MH; ++mi) {
        const int row = wr * WTR + qm * (MH * 16) + mi * 16 + l15;
#pragma unroll
        for (int ks = 0; ks < 2; ++ks)
          af[mi][ks] = *(const bf16x8*)(smem + cb + ((row * 128 + ks * 64 + g * 16) ^ xr));
      }
#pragma unroll
      for (int ni = 0; ni < 2; ++ni) {
        const int row = wc * 64 + qn * 32 + ni * 16 + l15;
#pragma unroll
        for (int ks = 0; ks < 2; ++ks)
          bfr[ni][ks] = *(const bf16x8*)(smem + cb + ASZ +
                                         ((row * 128 + ks * 64 + g * 16) ^ xr));
      }
      if constexpr (BM == 256) {
        if (q == 0 && pf) {
#pragma unroll
          for (int j = 0; j < 4; ++j)
            gld_lds16(Asrc + (size_t)(j * 64) * K + kcol, smem + ob + j * 8192 + ldsw);
        }
        if (q == 1 && pf) {
#pragma unroll
          for (int j = 0; j < 4; ++j)
            gld_lds16(Bsrc + (size_t)(j * 64) * K + kcol, smem + ob + ASZ + j * 8192 + ldsw);
        }
      } else {
        if (q == 0 && pf) {
#pragma unroll
          for (int j = 0; j < 2; ++j)
            gld_lds16(Asrc + (size_t)(j * 64) * K + kcol, smem + ob + j * 8192 + ldsw);
        }
        if (q == 1 && pf) {
#pragma unroll
          for (int j = 0; j < 2; ++j)
            gld_lds16(Bsrc + (size_t)(j * 64) * K + kcol, smem + ob + ASZ + j * 8192 + ldsw);
        }
        if (q == 2 && pf) {
#pragma unroll
          for (int j = 2; j < 4; ++j)
            gld_lds16(Bsrc + (size_t)(j * 64) * K + kcol, smem + ob + ASZ + j * 8192 + ldsw);
        }
      }
      __builtin_amdgcn_s_barrier();
      __builtin_amdgcn_s_setprio(1);
#pragma unroll
      for (int mi = 0; mi < MH; ++mi)
#pragma unroll
        for (int ni = 0; ni < 2; ++ni) {
          acc[qm * MH + mi][qn * 2 + ni] =
              MFMA_BF16(af[mi][0], bfr[ni][0], acc[qm * MH + mi][qn * 2 + ni]);
          acc[qm * MH + mi][qn * 2 + ni] =
              MFMA_BF16(af[mi][1], bfr[ni][1], acc[qm * MH + mi][qn * 2 + ni]);
        }
      __builtin_amdgcn_s_setprio(0);
      if (q < 3) __builtin_amdgcn_s_barrier();
    }
    asm volatile("s_waitcnt vmcnt(0)" ::: "memory");
    __builtin_amdgcn_s_barrier();
  }

  // epilogue; acc[ai][ci] -> wave rows ai*16, cols ci*16
  if constexpr (EPI == 2) {
#pragma unroll
    for (int ai = 0; ai < MF; ++ai)
#pragma unroll
      for (int ci = 0; ci < 4; ++ci) {
        const int n = n0 + wc * 64 + ci * 16 + l15;
        const float bn = bias[n];
#pragma unroll
        for (int r = 0; r < 4; ++r) {
          const size_t m = m0 + wr * WTR + ai * 16 + g * 4 + r;
          outf[m * N + n] = acc[ai][ci][r] + bn + resid[m * N + n];
        }
      }
  } else {
    char* wsl = smem + w * (WTR * 128);  // per-wave bounce [WTR rows][64 cols] bf16
#pragma unroll
    for (int ai = 0; ai < MF; ++ai)
#pragma unroll
      for (int ci = 0; ci < 4; ++ci) {
        float bn = 0.f;
        if constexpr (EPI == 3) bn = bias[n0 + wc * 64 + ci * 16 + l15];
#pragma unroll
        for (int r = 0; r < 4; ++r) {
          float v = acc[ai][ci][r];
          if constexpr (EPI == 3) {
            v += bn;
            const float inner = 0.7978845608028654f * (v + 0.044715f * v * v * v);
            v = 0.5f * v * (1.0f + tanhf(inner));
          }
          *(unsigned short*)(wsl + (ai * 16 + g * 4 + r) * 128 + (ci * 16 + l15) * 2) = bf16rn(v);
        }
      }
    // same-wave LDS RAW ordered by in-order DS pipe + compiler lgkmcnt
#pragma unroll
    for (int s = 0; s < WTR / 8; ++s) {
      const int row = s * 8 + (lane >> 3);
      bf16x8 vv = *(const bf16x8*)(wsl + row * 128 + (lane & 7) * 16);
      *(bf16x8*)(outb + (size_t)(m0 + wr * WTR + row) * N + n0 + wc * 64 + (lane & 7) * 8) = vv;
    }
  }
}

// ---------------- flash attention, causal, D=64, QB=128 (4 waves x 32 rows), KB=64 --------
// Q/K come from the fused QK buffer [8192][2048]: Q at cols 0-1023, K at cols 1024-2047.
__global__ __launch_bounds__(256) void attn_kernel(
    const unsigned short* __restrict__ qg, const unsigned short* __restrict__ kg,
    const unsigned short* __restrict__ vT, unsigned short* __restrict__ ctx)
{
  __shared__ char smem[34816];  // K 8KB | V_T 8KB | P 4x4608
  const int bh = blockIdx.x, b = bh >> 4, h = bh & 15;
  const int t = threadIdx.x, lane = t & 63, w = t >> 6, g = lane >> 4, l15 = lane & 15;
  char* Ks = smem;
  char* Vs = smem + 8192;
  char* Ps = smem + 16384 + w * 4608;

  const float SC = 0.18033688011112042f;  // 0.125 * log2(e)

  for (int pass = 0; pass < 2; ++pass) {
    const int qt = pass ? 15 - (int)blockIdx.y : (int)blockIdx.y;
    const int q0 = qt << 7;
    const int q0w = q0 + w * 32;

    bf16x8 qf[2][2];
#pragma unroll
    for (int mi = 0; mi < 2; ++mi)
#pragma unroll
      for (int ks = 0; ks < 2; ++ks)
        qf[mi][ks] = *(const bf16x8*)(qg + (size_t)(b * 2048 + q0w + mi * 16 + l15) * 2048 +
                                      h * 64 + ks * 32 + g * 8);

    f32x4 acc[2][4] = {};
    float lsum[2][4] = {};

    const int ntile = 2 * qt + 2;
    for (int kt = 0; kt < ntile; ++kt) {
      const int kv0 = kt << 6;
      __syncthreads();
#pragma unroll
      for (int it = 0; it < 2; ++it) {
        const int c = it * 256 + t;
        const int row = c >> 3;
        const int wb = (c & 7) << 4;
        const int sw = (wb ^ ((row & 7) << 4)) >> 1;
        gld_lds16(kg + (size_t)(b * 2048 + kv0 + row) * 2048 + h * 64 + sw,
                  Ks + ((it * 256 + w * 64) << 4));
        gld_lds16(vT + (size_t)(b * 1024 + h * 64 + row) * 2048 + kv0 + sw,
                  Vs + ((it * 256 + w * 64) << 4));
      }
      __syncthreads();

      f32x4 sf[2][4] = {};
#pragma unroll
      for (int nb = 0; nb < 4; ++nb) {
        const int krow = nb * 16 + l15;
#pragma unroll
        for (int ks = 0; ks < 2; ++ks) {
          bf16x8 kf = *(const bf16x8*)(Ks + krow * 128 +
                                       (((ks * 32 + g * 8) << 1) ^ ((krow & 7) << 4)));
          sf[0][nb] = MFMA_BF16(qf[0][ks], kf, sf[0][nb]);
          sf[1][nb] = MFMA_BF16(qf[1][ks], kf, sf[1][nb]);
        }
      }
      if (kv0 + 63 > q0w) {
#pragma unroll
        for (int mi = 0; mi < 2; ++mi)
#pragma unroll
          for (int nb = 0; nb < 4; ++nb)
#pragma unroll
            for (int r = 0; r < 4; ++r) {
              const int qq = q0w + mi * 16 + 4 * g + r;
              const int kk = kv0 + nb * 16 + l15;
              if (kk > qq) sf[mi][nb][r] = -__builtin_inff();
            }
      }
#pragma unroll
      for (int mi = 0; mi < 2; ++mi)
#pragma unroll
        for (int nb = 0; nb < 4; ++nb)
#pragma unroll
          for (int r = 0; r < 4; ++r) {
            const float p = exp2f(__builtin_fmaf(sf[mi][nb][r], SC, -4.0f));
            sf[mi][nb][r] = p;
            lsum[mi][r] += p;
          }
#pragma unroll
      for (int mi = 0; mi < 2; ++mi)
#pragma unroll
        for (int nb = 0; nb < 4; ++nb)
#pragma unroll
          for (int r = 0; r < 4; ++r)
            *(unsigned short*)(Ps + (mi * 16 + 4 * g + r) * 144 + ((nb * 16 + l15) << 1)) =
                bf16rn(sf[mi][nb][r]);
      asm volatile("s_waitcnt lgkmcnt(0)" ::: "memory");
#pragma unroll
      for (int mi = 0; mi < 2; ++mi)
#pragma unroll
        for (int ks = 0; ks < 2; ++ks) {
          bf16x8 pa = *(const bf16x8*)(Ps + (mi * 16 + l15) * 144 + ((ks * 32 + g * 8) << 1));
#pragma unroll
          for (int nb = 0; nb < 4; ++nb) {
            const int drow = nb * 16 + l15;
            bf16x8 vb = *(const bf16x8*)(Vs + drow * 128 +
                                         (((ks * 32 + g * 8) << 1) ^ ((drow & 7) << 4)));
            acc[mi][nb] = MFMA_BF16(pa, vb, acc[mi][nb]);
          }
        }
    }
#pragma unroll
    for (int mi = 0; mi < 2; ++mi)
#pragma unroll
      for (int r = 0; r < 4; ++r) {
        float s = lsum[mi][r];
        s += __shfl_xor(s, 1);
        s += __shfl_xor(s, 2);
        s += __shfl_xor(s, 4);
        s += __shfl_xor(s, 8);
        lsum[mi][r] = s;
      }
#pragma unroll
    for (int mi = 0; mi < 2; ++mi) {
      float inv[4];
#pragma unroll
      for (int r = 0; r < 4; ++r) inv[r] = 1.0f / lsum[mi][r];
#pragma unroll
      for (int nb = 0; nb < 4; ++nb)
#pragma unroll
        for (int r = 0; r < 4; ++r)
          ctx[(size_t)(b * 2048 + q0w + mi * 16 + 4 * g + r) * 1024 + h * 64 + nb * 16 + l15] =
              bf16rn(acc[mi][nb][r] * inv[r]);
    }
  }
}

extern "C" void kernel_launch(void* const* d_in, const int* in_sizes, int n_in,
                              void* d_out, int out_size, void* d_ws, size_t ws_size,
                              hipStream_t stream)
{
  const float* x   = (const float*)d_in[0];
  const float* l1s = (const float*)d_in[1];
  const float* l1b = (const float*)d_in[2];
  const float* l2s = (const float*)d_in[3];
  const float* l2b = (const float*)d_in[4];
  const float* Wq  = (const float*)d_in[5];
  const float* Wk  = (const float*)d_in[6];
  const float* Wv  = (const float*)d_in[7];
  const float* Wo  = (const float*)d_in[8];
  const float* bo  = (const float*)d_in[9];
  const float* Wfc = (const float*)d_in[10];
  const float* bfc = (const float*)d_in[11];
  const float* Wpj = (const float*)d_in[12];
  const float* bpj = (const float*)d_in[13];
  float* out = (float*)d_out;
  char* ws = (char*)d_ws;

  // workspace layout (bytes)
  unsigned short* wT   = (unsigned short*)ws;                // 24MB: [wqT wkT][wvT][woT][wfcT][wpjT]
  unsigned short* wqkT = wT;                                 // [2048][1024] fused Q|K
  unsigned short* wvT  = wT + 2097152u;
  unsigned short* woT  = wT + 3145728u;
  unsigned short* wfcT = wT + 4194304u;
  unsigned short* wpjT = wT + 8388608u;
  unsigned short* ln1x = (unsigned short*)(ws + 25165824u);  // 16MB
  unsigned short* qkb  = (unsigned short*)(ws + 41943040u);  // 32MB [8192][2048] fused Q|K out
  unsigned short* vTb  = (unsigned short*)(ws + 75497472u);  // 16MB [b*1024+h*64+d][2048]
  unsigned short* ctx  = (unsigned short*)(ws + 92274688u);  // 16MB (reused as ln2x)
  unsigned short* ln2x = ctx;
  float* hbuf          = (float*)(ws + 109051904u);          // 32MB
  unsigned short* fcb  = (unsigned short*)(ws + 25165824u);  // 64MB, reuses ln1x..vTb region

  convT_kernel<<<3072, 256, 0, stream>>>(Wq, Wk, Wv, Wo, Wfc, Wpj, wT);
  ln_kernel<<<8192, 256, 0, stream>>>(x, l1s, l1b, ln1x);
  // fused Q+K GEMM: [8192][1024] x [2048][1024]^T -> [8192][2048]
  gemm256<0, 256><<<256, 512, 131072, stream>>>(ln1x, wqkT, 8192, 2048, 1024, 2,
                                                qkb, nullptr, nullptr, nullptr);
  gemm_bt<1><<<dim3(64, 8), 256, 0, stream>>>(ln1x, wvT, 8192, 1024, 1024,
                                              vTb, nullptr, nullptr, nullptr);
  attn_kernel<<<dim3(64, 8), 256, 0, stream>>>(qkb, qkb + 1024, vTb, ctx);
  gemm256<2, 128><<<256, 512, 98304, stream>>>(ctx, woT, 8192, 1024, 1024, 3,
                                               nullptr, hbuf, bo, x);
  ln_kernel<<<8192, 256, 0, stream>>>(hbuf, l2s, l2b, ln2x);
  gemm256<3, 256><<<512, 512, 131072, stream>>>(ln2x, wfcT, 8192, 4096, 1024, 2,
                                                fcb, nullptr, bfc, nullptr);
  gemm256<2, 128><<<256, 512, 98304, stream>>>(fcb, wpjT, 8192, 1024, 4096, 3,
                                               nullptr, out, bpj, hbuf);
}